// Round 20
// baseline (116.714 us; speedup 1.0000x reference)
//
#include <hip/hip_runtime.h>

#define HIDDEN 1024
#define NB 8
#define SEQ 2048
#define DH 64

typedef long long i64;
typedef unsigned short u16;
typedef __attribute__((ext_vector_type(8))) _Float16 half8;  // 4 VGPRs = 8 fp16
typedef __attribute__((ext_vector_type(4))) float f32x4;

#define MFMA16F __builtin_amdgcn_mfma_f32_16x16x32_f16

__device__ __forceinline__ u16 f2h(float x) {
    _Float16 h = (_Float16)x;                 // RNE
    return __builtin_bit_cast(u16, h);
}
__device__ __forceinline__ void gl_lds16(const void* g, void* l) {
    __builtin_amdgcn_global_load_lds(
        (const __attribute__((address_space(1))) unsigned int*)g,
        (__attribute__((address_space(3))) unsigned int*)l, 16, 0, 0);
}

// ---------------------------------------------------------------------------
// Prepass: W[1024][64] (x3) -> Wimg[te][p][n][pos] fp16, p = 16 phases of
// BK=64, n = out col, pos = 16B block (8 per row); position pos holds global
// k-chunk (pos ^ (n&7)). (byte-identical to round-19 passing version)
// ---------------------------------------------------------------------------
__global__ __launch_bounds__(256) void wimg_prep16(
    const float* __restrict__ Wq, const float* __restrict__ Wk, const float* __restrict__ Wv,
    u16* __restrict__ Wimg)
{
    const int t = blockIdx.x * 256 + threadIdx.x;   // 24576 threads
    const int te = t >> 13;
    const int rem = t & 8191;
    const int p = rem >> 9;                          // 0..15
    const int rem2 = rem & 511;
    const int n = rem2 >> 3;                         // 0..63
    const int pos = rem2 & 7;                        // 16B block in row
    const float* W = te == 0 ? Wq : te == 1 ? Wk : Wv;
    const int g = pos ^ (n & 7);
    const int k0 = p * 64 + g * 8;
    u16* dst = Wimg + (i64)t * 8;
    #pragma unroll
    for (int j = 0; j < 8; ++j)
        dst[j] = f2h(W[(i64)(k0 + j) * DH + n]);
}

// ---------------------------------------------------------------------------
// Projection v14: A on PLAIN float4 loads (depth-3 register ring, high MLP,
// the attn-mask-proven path), W OFF the global critical path entirely:
// staged per K-quarter (32KB) into single-buffered LDS from the pre-swizzled
// image. Tile 64 rows x 64 cols, 4 waves (wave w: rows 16w..16w+15),
// grid (256,3) = 768 blocks = 3/CU all-resident. Per step: cvt 8, 8
// conflict-free ds_read (v13 formula), 8 MFMA, issue A(s+3). 8 barriers
// total (2 per quarter). Operation-identical numerics to v13 (4.88e-4).
// ---------------------------------------------------------------------------
__global__ __launch_bounds__(256) void proj_mfma14(
    const float* __restrict__ qh, const float* __restrict__ kh, const float* __restrict__ vh,
    const u16* __restrict__ Wimg,
    const float* __restrict__ bq, const float* __restrict__ bk, const float* __restrict__ bv,
    u16* __restrict__ Qb, u16* __restrict__ Kb, u16* __restrict__ Vt)
{
    const int te = blockIdx.y;
    const float* A    = te == 0 ? qh : te == 1 ? kh : vh;
    const float* bias = te == 0 ? bq : te == 1 ? bk : bv;
    const int row0 = blockIdx.x << 6;          // 256 tiles of 64 rows
    const int t = threadIdx.x;
    const int w = t >> 6, lane = t & 63;
    const int lr = lane & 15, lg = lane >> 4;
    const int wr = w << 4;                     // wave row offset: 0,16,32,48

    __shared__ __attribute__((aligned(16))) u16 WL[16384];   // 32 KB, one K-quarter

    const u16* Wte = Wimg + (i64)te * 65536;
    const float* arow = A + (i64)(row0 + wr + lr) * HIDDEN + (lg << 3);

    f32x4 acc[4] = {};
    float4 ab[3][4];                           // depth-3 A ring (static idx)

#define LDA(slot, P) { \
        const int c_ = ((P) & 15) << 6; \
        ab[slot][0] = *(const float4*)(arow + c_); \
        ab[slot][1] = *(const float4*)(arow + c_ + 4); \
        ab[slot][2] = *(const float4*)(arow + c_ + 32); \
        ab[slot][3] = *(const float4*)(arow + c_ + 36); }

    LDA(0, 0) LDA(1, 1) LDA(2, 2)

    #pragma unroll
    for (int kq = 0; kq < 4; ++kq) {
        __syncthreads();                       // prev quarter's reads done
        // stage quarter kq: 32KB, 8x1KB linear gl_lds per wave
        #pragma unroll
        for (int j = 0; j < 8; ++j)
            gl_lds16(Wte + kq * 16384 + w * 4096 + j * 512 + (lane << 3),
                     &WL[w * 4096 + j * 512]);
        asm volatile("s_waitcnt vmcnt(0)" ::: "memory");
        __syncthreads();                       // quarter visible

        #pragma unroll
        for (int s = 0; s < 4; ++s) {
            const int p = kq * 4 + s;          // global phase 0..15 (static)
            const int slot = p % 3;
            half8 a0, a1;
            a0[0] = (_Float16)ab[slot][0].x; a0[1] = (_Float16)ab[slot][0].y;
            a0[2] = (_Float16)ab[slot][0].z; a0[3] = (_Float16)ab[slot][0].w;
            a0[4] = (_Float16)ab[slot][1].x; a0[5] = (_Float16)ab[slot][1].y;
            a0[6] = (_Float16)ab[slot][1].z; a0[7] = (_Float16)ab[slot][1].w;
            a1[0] = (_Float16)ab[slot][2].x; a1[1] = (_Float16)ab[slot][2].y;
            a1[2] = (_Float16)ab[slot][2].z; a1[3] = (_Float16)ab[slot][2].w;
            a1[4] = (_Float16)ab[slot][3].x; a1[5] = (_Float16)ab[slot][3].y;
            a1[6] = (_Float16)ab[slot][3].z; a1[7] = (_Float16)ab[slot][3].w;
            LDA(slot, p + 3)                   // refill ring (wrap-clamped)
            #pragma unroll
            for (int nt = 0; nt < 4; ++nt) {
                const int n = nt * 16 + lr;
                const half8 b = *(const half8*)&WL[s * 4096 + n * 64 +
                                                  (((lg) ^ (n & 7)) << 3)];
                acc[nt] = MFMA16F(a0, b, acc[nt], 0, 0, 0);
            }
            #pragma unroll
            for (int nt = 0; nt < 4; ++nt) {
                const int n = nt * 16 + lr;
                const half8 b = *(const half8*)&WL[s * 4096 + n * 64 +
                                                  (((4 + lg) ^ (n & 7)) << 3)];
                acc[nt] = MFMA16F(a1, b, acc[nt], 0, 0, 0);
            }
        }
    }
#undef LDA

    // epilogue: D layout col=lane&15 (within nt), row=(lane>>4)*4+reg
    #pragma unroll
    for (int nt = 0; nt < 4; ++nt) {
        const int col = nt * 16 + lr;
        const float bb = bias[col];
        #pragma unroll
        for (int r = 0; r < 4; ++r) {
            const i64 grow = row0 + wr + (lg << 2) + r;
            const u16 v = f2h(acc[nt][r] + bb);
            if (te == 0)      Qb[grow * DH + col] = v;
            else if (te == 1) Kb[grow * DH + col] = v;
            else {
                const i64 bb2 = grow >> 11, key = grow & 2047;
                Vt[(bb2 * DH + col) * SEQ + key] = v;
            }
        }
    }
}

// ---------------------------------------------------------------------------
// Attention: 1024 single-wave blocks + XCD swizzle.
// (byte-identical to the round-19 passing version)
// ---------------------------------------------------------------------------
__global__ __launch_bounds__(64) void attn_mfma(
    const u16* __restrict__ Qb, const u16* __restrict__ Kb, const u16* __restrict__ Vt,
    const int* __restrict__ mask, float* __restrict__ out)
{
    __shared__ __attribute__((aligned(16))) u16 Kl[2][64 * 64];
    __shared__ __attribute__((aligned(16))) u16 Vl[2][64 * 64];
    __shared__ __attribute__((aligned(16))) u16 Pl[16][72];

    const int lane = threadIdx.x;
    const int lr = lane & 15, lg = lane >> 4;
    const int bid = blockIdx.x;
    const int id2 = (bid & 7) * 128 + (bid >> 3);   // bijective XCD swizzle
    const int b  = id2 >> 7;
    const int q0 = (id2 & 127) << 4;

    const i64 qrow = (i64)b * SEQ + q0 + lr;
    const half8 qf0 = *(const half8*)(Qb + qrow * DH + lg * 8);
    const half8 qf1 = *(const half8*)(Qb + qrow * DH + 32 + lg * 8);

    const int srow = lane >> 3;   // 0..7 (+8i)
    const int scb  = lane & 7;    // 16B block

    f32x4 oacc[4] = {};
    float rs0 = 0.f, rs1 = 0.f, rs2 = 0.f, rs3 = 0.f;

    // prologue: stage tile 0 into buf 0 (16 loads)
    {
        const i64 kbase = (i64)b * SEQ;
        #pragma unroll
        for (int i = 0; i < 8; ++i) {
            int row = i * 8 + srow, cb = scb ^ (row & 7);
            gl_lds16(Kb + (kbase + row) * DH + cb * 8, &Kl[0][i * 512]);
        }
        #pragma unroll
        for (int i = 0; i < 8; ++i) {
            int row = i * 8 + srow, cb = scb ^ (row & 7);
            gl_lds16(Vt + ((i64)b * DH + row) * SEQ + cb * 8, &Vl[0][i * 512]);
        }
    }

    #pragma unroll 1
    for (int t = 0; t < 32; ++t) {
        const int kt = t * 64;
        const int buf = t & 1;

        int mv[16];
        #pragma unroll
        for (int tt = 0; tt < 4; ++tt)
            #pragma unroll
            for (int r = 0; r < 4; ++r)
                mv[tt * 4 + r] =
                    mask[((i64)b * SEQ + q0 + lg * 4 + r) * SEQ + kt + tt * 16 + lr];

        if (t < 31) {
            const int kn = kt + 64;
            const i64 kbase = (i64)b * SEQ + kn;
            #pragma unroll
            for (int i = 0; i < 8; ++i) {
                int row = i * 8 + srow, cb = scb ^ (row & 7);
                gl_lds16(Kb + (kbase + row) * DH + cb * 8, &Kl[buf ^ 1][i * 512]);
            }
            #pragma unroll
            for (int i = 0; i < 8; ++i) {
                int row = i * 8 + srow, cb = scb ^ (row & 7);
                gl_lds16(Vt + ((i64)b * DH + row) * SEQ + kn + cb * 8, &Vl[buf ^ 1][i * 512]);
            }
            asm volatile("s_waitcnt vmcnt(32)" ::: "memory");
        } else {
            asm volatile("s_waitcnt vmcnt(16)" ::: "memory");
        }

        f32x4 sacc[4] = {};
        #pragma unroll
        for (int tt = 0; tt < 4; ++tt) {
            int row = tt * 16 + lr, x = row & 7;
            half8 k0 = *(const half8*)&Kl[buf][row * 64 + ((lg) ^ x) * 8];
            half8 k1 = *(const half8*)&Kl[buf][row * 64 + ((lg + 4) ^ x) * 8];
            sacc[tt] = MFMA16F(qf0, k0, sacc[tt], 0, 0, 0);
            sacc[tt] = MFMA16F(qf1, k1, sacc[tt], 0, 0, 0);
        }

        #pragma unroll
        for (int tt = 0; tt < 4; ++tt) {
            #pragma unroll
            for (int r = 0; r < 4; ++r) {
                float p = (mv[tt * 4 + r] != 0) ? __expf(sacc[tt][r] * 0.125f) : 0.0f;
                if      (r == 0) rs0 += p;
                else if (r == 1) rs1 += p;
                else if (r == 2) rs2 += p;
                else             rs3 += p;
                Pl[lg * 4 + r][tt * 16 + lr] = f2h(p);
            }
        }

        const half8 p0 = *(const half8*)&Pl[lr][lg * 8];
        const half8 p1 = *(const half8*)&Pl[lr][32 + lg * 8];
        #pragma unroll
        for (int vt = 0; vt < 4; ++vt) {
            int row = vt * 16 + lr, x = row & 7;
            half8 v0 = *(const half8*)&Vl[buf][row * 64 + ((lg) ^ x) * 8];
            half8 v1 = *(const half8*)&Vl[buf][row * 64 + ((lg + 4) ^ x) * 8];
            oacc[vt] = MFMA16F(p0, v0, oacc[vt], 0, 0, 0);
            oacc[vt] = MFMA16F(p1, v1, oacc[vt], 0, 0, 0);
        }
    }

    float rs[4] = {rs0, rs1, rs2, rs3};
    #pragma unroll
    for (int r = 0; r < 4; ++r) {
        float v = rs[r];
        v += __shfl_xor(v, 1, 64);
        v += __shfl_xor(v, 2, 64);
        v += __shfl_xor(v, 4, 64);
        v += __shfl_xor(v, 8, 64);
        rs[r] = 1.0f / v;
    }
    #pragma unroll
    for (int vt = 0; vt < 4; ++vt)
        #pragma unroll
        for (int r = 0; r < 4; ++r)
            out[((i64)b * SEQ + q0 + lg * 4 + r) * DH + vt * 16 + lr] = oacc[vt][r] * rs[r];
}

extern "C" void kernel_launch(void* const* d_in, const int* in_sizes, int n_in,
                              void* d_out, int out_size, void* d_ws, size_t ws_size,
                              hipStream_t stream) {
    const float* kh   = (const float*)d_in[0];
    const float* qh   = (const float*)d_in[1];
    const float* vh   = (const float*)d_in[2];
    const int*   mask = (const int*)  d_in[3];
    const float* Wq   = (const float*)d_in[4];
    const float* bq   = (const float*)d_in[5];
    const float* Wk   = (const float*)d_in[6];
    const float* bk   = (const float*)d_in[7];
    const float* Wv   = (const float*)d_in[8];
    const float* bv   = (const float*)d_in[9];
    float* out = (float*)d_out;

    u16* Wimg = (u16*)d_ws;                      // 3*16*4096 u16 = 384 KB
    u16* Qb   = Wimg + 3 * 16 * 4096;            // 2 MB each
    u16* Kb   = Qb + (i64)NB * SEQ * DH;
    u16* Vt   = Kb + (i64)NB * SEQ * DH;         // [b][vd][key]

    wimg_prep16<<<96, 256, 0, stream>>>(Wq, Wk, Wv, Wimg);
    proj_mfma14<<<dim3(256, 3), 256, 0, stream>>>(qh, kh, vh, Wimg,
                                                  bq, bk, bv, Qb, Kb, Vt);
    attn_mfma<<<1024, 64, 0, stream>>>(Qb, Kb, Vt, mask, out);
}

// Round 21
// 116.678 us; speedup vs baseline: 1.0003x; 1.0003x over previous
//
#include <hip/hip_runtime.h>

#define HIDDEN 1024
#define NB 8
#define SEQ 2048
#define DH 64

typedef long long i64;
typedef unsigned short u16;
typedef __attribute__((ext_vector_type(8))) _Float16 half8;  // 4 VGPRs = 8 fp16
typedef __attribute__((ext_vector_type(4))) float f32x4;

#define MFMA16F __builtin_amdgcn_mfma_f32_16x16x32_f16

__device__ __forceinline__ u16 f2h(float x) {
    _Float16 h = (_Float16)x;                 // RNE
    return __builtin_bit_cast(u16, h);
}
__device__ __forceinline__ void gl_lds16(const void* g, void* l) {
    __builtin_amdgcn_global_load_lds(
        (const __attribute__((address_space(1))) unsigned int*)g,
        (__attribute__((address_space(3))) unsigned int*)l, 16, 0, 0);
}

// ---------------------------------------------------------------------------
// Prepass: W[1024][64] (x3) -> Wimg[te][p][n][pos] fp16, p = 16 phases of
// BK=64, n = out col, pos = 16B block (8 per row); position pos holds global
// k-chunk (pos ^ (n&7)). (byte-identical to round-19 passing version)
// ---------------------------------------------------------------------------
__global__ __launch_bounds__(256) void wimg_prep16(
    const float* __restrict__ Wq, const float* __restrict__ Wk, const float* __restrict__ Wv,
    u16* __restrict__ Wimg)
{
    const int t = blockIdx.x * 256 + threadIdx.x;   // 24576 threads
    const int te = t >> 13;
    const int rem = t & 8191;
    const int p = rem >> 9;                          // 0..15
    const int rem2 = rem & 511;
    const int n = rem2 >> 3;                         // 0..63
    const int pos = rem2 & 7;                        // 16B block in row
    const float* W = te == 0 ? Wq : te == 1 ? Wk : Wv;
    const int g = pos ^ (n & 7);
    const int k0 = p * 64 + g * 8;
    u16* dst = Wimg + (i64)t * 8;
    #pragma unroll
    for (int j = 0; j < 8; ++j)
        dst[j] = f2h(W[(i64)(k0 + j) * DH + n]);
}

// ---------------------------------------------------------------------------
// Projection v13 (session best): v8 skeleton x v12 bodies,
// 64x64 tile, BK=64, 16 phases, LDS 48KB -> 3 blocks/CU, all resident.
// A-from-HBM/L3 ~2.4 TB/s effective is this op's measured platform floor
// (14 variants: load-type/TLP/depth/barrier/byte-count invariant).
// ---------------------------------------------------------------------------
__global__ __launch_bounds__(256) void proj_mfma13(
    const float* __restrict__ qh, const float* __restrict__ kh, const float* __restrict__ vh,
    const u16* __restrict__ Wimg,
    const float* __restrict__ bq, const float* __restrict__ bk, const float* __restrict__ bv,
    u16* __restrict__ Qb, u16* __restrict__ Kb, u16* __restrict__ Vt)
{
    const int te = blockIdx.y;
    const float* A    = te == 0 ? qh : te == 1 ? kh : vh;
    const float* bias = te == 0 ? bq : te == 1 ? bk : bv;
    const int row0 = blockIdx.x << 6;          // 256 tiles of 64 rows
    const int t = threadIdx.x;
    const int w = t >> 6, lane = t & 63;
    const int lr = lane & 15, lg = lane >> 4;
    const int wr = w << 4;                     // wave row offset: 0,16,32,48

    __shared__ __attribute__((aligned(16))) float AL[2][64 * 64];   // 16KB x2
    __shared__ __attribute__((aligned(16))) u16  WL[2][64 * 64];    // 8KB x2

    const u16* Wte = Wimg + (i64)te * 16 * 4096;

    const float* asrc[4]; int adst[4];
    #pragma unroll
    for (int i = 0; i < 4; ++i) {
        const int ar = wr + 4 * i + (lane >> 4);             // slab row
        const int ab = (lane & 15) ^ (ar & 15);              // source 16B block
        asrc[i] = A + (i64)(row0 + ar) * HIDDEN + (ab << 2);
        adst[i] = (wr + 4 * i) * 64;
    }
    const u16* wsrc[2]; int wdst[2];
    #pragma unroll
    for (int j = 0; j < 2; ++j) {
        const int n0 = wr + 8 * j;
        wsrc[j] = Wte + n0 * 64 + (lane << 3);               // linear image
        wdst[j] = n0 * 64;
    }

    f32x4 acc[4] = {};

#define STAGE(P, B) { \
        _Pragma("unroll") \
        for (int i_ = 0; i_ < 4; ++i_) \
            gl_lds16(asrc[i_] + (P) * 64, &AL[B][adst[i_]]); \
        _Pragma("unroll") \
        for (int j_ = 0; j_ < 2; ++j_) \
            gl_lds16(wsrc[j_] + (P) * 4096, &WL[B][wdst[j_]]); }

#define COMPUTE(B) { \
        _Pragma("unroll") \
        for (int ks = 0; ks < 2; ++ks) { \
            const int b0 = ks * 8 + lg * 2; \
            const float4 fa = *(const float4*)&AL[B][(wr + lr) * 64 + ((b0 ^ lr) << 2)]; \
            const float4 fb = *(const float4*)&AL[B][(wr + lr) * 64 + (((b0 + 1) ^ lr) << 2)]; \
            half8 a; \
            a[0] = (_Float16)fa.x; a[1] = (_Float16)fa.y; \
            a[2] = (_Float16)fa.z; a[3] = (_Float16)fa.w; \
            a[4] = (_Float16)fb.x; a[5] = (_Float16)fb.y; \
            a[6] = (_Float16)fb.z; a[7] = (_Float16)fb.w; \
            _Pragma("unroll") \
            for (int nt = 0; nt < 4; ++nt) { \
                const int n = nt * 16 + lr; \
                const int pos = (ks * 4 + lg) ^ (n & 7); \
                const half8 b = *(const half8*)&WL[B][n * 64 + (pos << 3)]; \
                acc[nt] = MFMA16F(a, b, acc[nt], 0, 0, 0); \
            } \
        } }

    STAGE(0, 0)

    int buf = 0;
    #pragma unroll 1
    for (int p = 0; p < 16; ++p) {
        asm volatile("s_waitcnt vmcnt(0)" ::: "memory");   // stage(p) done
        __syncthreads();                                    // visible; buf^1 free
        if (p < 15) STAGE(p + 1, buf ^ 1)
        COMPUTE(buf)
        buf ^= 1;
    }
#undef STAGE
#undef COMPUTE

    #pragma unroll
    for (int nt = 0; nt < 4; ++nt) {
        const int col = nt * 16 + lr;
        const float bb = bias[col];
        #pragma unroll
        for (int r = 0; r < 4; ++r) {
            const i64 grow = row0 + wr + (lg << 2) + r;
            const u16 v = f2h(acc[nt][r] + bb);
            if (te == 0)      Qb[grow * DH + col] = v;
            else if (te == 1) Kb[grow * DH + col] = v;
            else {
                const i64 bb2 = grow >> 11, key = grow & 2047;
                Vt[(bb2 * DH + col) * SEQ + key] = v;
            }
        }
    }
}

// ---------------------------------------------------------------------------
// Attention: 1024 single-wave blocks + bijective XCD swizzle (batch->XCD:
// each XCD's L2 holds only its own batch's 512KB K/V). Counted vmcnt,
// no barriers, no-max softmax. (byte-identical to round-19 passing version)
// ---------------------------------------------------------------------------
__global__ __launch_bounds__(64) void attn_mfma(
    const u16* __restrict__ Qb, const u16* __restrict__ Kb, const u16* __restrict__ Vt,
    const int* __restrict__ mask, float* __restrict__ out)
{
    __shared__ __attribute__((aligned(16))) u16 Kl[2][64 * 64];
    __shared__ __attribute__((aligned(16))) u16 Vl[2][64 * 64];
    __shared__ __attribute__((aligned(16))) u16 Pl[16][72];

    const int lane = threadIdx.x;
    const int lr = lane & 15, lg = lane >> 4;
    const int bid = blockIdx.x;
    const int id2 = (bid & 7) * 128 + (bid >> 3);   // bijective XCD swizzle
    const int b  = id2 >> 7;
    const int q0 = (id2 & 127) << 4;

    const i64 qrow = (i64)b * SEQ + q0 + lr;
    const half8 qf0 = *(const half8*)(Qb + qrow * DH + lg * 8);
    const half8 qf1 = *(const half8*)(Qb + qrow * DH + 32 + lg * 8);

    const int srow = lane >> 3;   // 0..7 (+8i)
    const int scb  = lane & 7;    // 16B block

    f32x4 oacc[4] = {};
    float rs0 = 0.f, rs1 = 0.f, rs2 = 0.f, rs3 = 0.f;

    // prologue: stage tile 0 into buf 0 (16 loads)
    {
        const i64 kbase = (i64)b * SEQ;
        #pragma unroll
        for (int i = 0; i < 8; ++i) {
            int row = i * 8 + srow, cb = scb ^ (row & 7);
            gl_lds16(Kb + (kbase + row) * DH + cb * 8, &Kl[0][i * 512]);
        }
        #pragma unroll
        for (int i = 0; i < 8; ++i) {
            int row = i * 8 + srow, cb = scb ^ (row & 7);
            gl_lds16(Vt + ((i64)b * DH + row) * SEQ + cb * 8, &Vl[0][i * 512]);
        }
    }

    #pragma unroll 1
    for (int t = 0; t < 32; ++t) {
        const int kt = t * 64;
        const int buf = t & 1;

        int mv[16];
        #pragma unroll
        for (int tt = 0; tt < 4; ++tt)
            #pragma unroll
            for (int r = 0; r < 4; ++r)
                mv[tt * 4 + r] =
                    mask[((i64)b * SEQ + q0 + lg * 4 + r) * SEQ + kt + tt * 16 + lr];

        if (t < 31) {
            const int kn = kt + 64;
            const i64 kbase = (i64)b * SEQ + kn;
            #pragma unroll
            for (int i = 0; i < 8; ++i) {
                int row = i * 8 + srow, cb = scb ^ (row & 7);
                gl_lds16(Kb + (kbase + row) * DH + cb * 8, &Kl[buf ^ 1][i * 512]);
            }
            #pragma unroll
            for (int i = 0; i < 8; ++i) {
                int row = i * 8 + srow, cb = scb ^ (row & 7);
                gl_lds16(Vt + ((i64)b * DH + row) * SEQ + kn + cb * 8, &Vl[buf ^ 1][i * 512]);
            }
            asm volatile("s_waitcnt vmcnt(32)" ::: "memory");
        } else {
            asm volatile("s_waitcnt vmcnt(16)" ::: "memory");
        }

        f32x4 sacc[4] = {};
        #pragma unroll
        for (int tt = 0; tt < 4; ++tt) {
            int row = tt * 16 + lr, x = row & 7;
            half8 k0 = *(const half8*)&Kl[buf][row * 64 + ((lg) ^ x) * 8];
            half8 k1 = *(const half8*)&Kl[buf][row * 64 + ((lg + 4) ^ x) * 8];
            sacc[tt] = MFMA16F(qf0, k0, sacc[tt], 0, 0, 0);
            sacc[tt] = MFMA16F(qf1, k1, sacc[tt], 0, 0, 0);
        }

        #pragma unroll
        for (int tt = 0; tt < 4; ++tt) {
            #pragma unroll
            for (int r = 0; r < 4; ++r) {
                float p = (mv[tt * 4 + r] != 0) ? __expf(sacc[tt][r] * 0.125f) : 0.0f;
                if      (r == 0) rs0 += p;
                else if (r == 1) rs1 += p;
                else if (r == 2) rs2 += p;
                else             rs3 += p;
                Pl[lg * 4 + r][tt * 16 + lr] = f2h(p);
            }
        }

        const half8 p0 = *(const half8*)&Pl[lr][lg * 8];
        const half8 p1 = *(const half8*)&Pl[lr][32 + lg * 8];
        #pragma unroll
        for (int vt = 0; vt < 4; ++vt) {
            int row = vt * 16 + lr, x = row & 7;
            half8 v0 = *(const half8*)&Vl[buf][row * 64 + ((lg) ^ x) * 8];
            half8 v1 = *(const half8*)&Vl[buf][row * 64 + ((lg + 4) ^ x) * 8];
            oacc[vt] = MFMA16F(p0, v0, oacc[vt], 0, 0, 0);
            oacc[vt] = MFMA16F(p1, v1, oacc[vt], 0, 0, 0);
        }
    }

    float rs[4] = {rs0, rs1, rs2, rs3};
    #pragma unroll
    for (int r = 0; r < 4; ++r) {
        float v = rs[r];
        v += __shfl_xor(v, 1, 64);
        v += __shfl_xor(v, 2, 64);
        v += __shfl_xor(v, 4, 64);
        v += __shfl_xor(v, 8, 64);
        rs[r] = 1.0f / v;
    }
    #pragma unroll
    for (int vt = 0; vt < 4; ++vt)
        #pragma unroll
        for (int r = 0; r < 4; ++r)
            out[((i64)b * SEQ + q0 + lg * 4 + r) * DH + vt * 16 + lr] = oacc[vt][r] * rs[r];
}

extern "C" void kernel_launch(void* const* d_in, const int* in_sizes, int n_in,
                              void* d_out, int out_size, void* d_ws, size_t ws_size,
                              hipStream_t stream) {
    const float* kh   = (const float*)d_in[0];
    const float* qh   = (const float*)d_in[1];
    const float* vh   = (const float*)d_in[2];
    const int*   mask = (const int*)  d_in[3];
    const float* Wq   = (const float*)d_in[4];
    const float* bq   = (const float*)d_in[5];
    const float* Wk   = (const float*)d_in[6];
    const float* bk   = (const float*)d_in[7];
    const float* Wv   = (const float*)d_in[8];
    const float* bv   = (const float*)d_in[9];
    float* out = (float*)d_out;

    u16* Wimg = (u16*)d_ws;                      // 3*16*4096 u16 = 384 KB
    u16* Qb   = Wimg + 3 * 16 * 4096;            // 2 MB each
    u16* Kb   = Qb + (i64)NB * SEQ * DH;
    u16* Vt   = Kb + (i64)NB * SEQ * DH;         // [b][vd][key]

    wimg_prep16<<<96, 256, 0, stream>>>(Wq, Wk, Wv, Wimg);
    proj_mfma13<<<dim3(256, 3), 256, 0, stream>>>(qh, kh, vh, Wimg,
                                                  bq, bk, bv, Qb, Kb, Vt);
    attn_mfma<<<1024, 64, 0, stream>>>(Qb, Kb, Vt, mask, out);
}